// Round 4
// baseline (226.690 us; speedup 1.0000x reference)
//
#include <hip/hip_runtime.h>
#include <math.h>

// FilteredCrossEntropyLoss: B=1048576 rows, C=64 classes.
// loss = (1/B) * sum_rows [ K(t) + log(sum_c exp(p_c)) - sum_j f_j * p[col_j] ]
// All filters sum to 1; K(t)=sum f log f. No max-subtraction (inputs N(0,1)).
//
// Round-4 structure:
//  - 16-lane group per row, 2 rows per group per iter (8 rows/wave-iter):
//    3 VMEM instr / 8 rows (2x dwordx4 + 1x int2), nontemporal (read-once).
//  - weights computed in-lane (quadratic in d=|j-2|), edge rows fixed up
//    under a __any gate; wp stays per-lane (collected by the final wave sum),
//    only the exp-sum needs the 4-step DPP reduce. Zero DS ops in the loop.
//  - single kernel: block partials -> fixed-point (2^38) int64 atomicAdd
//    (bit-deterministic) + counter; last block writes d_out. 16 B memset.

#define THREADS 256
#define NBLOCKS 2048
#define RPI 8              // rows per wave-iteration

typedef float  f32x4 __attribute__((ext_vector_type(4)));
typedef int    i32x2 __attribute__((ext_vector_type(2)));

__device__ __forceinline__ float dpp_add16(float x) {
    // sum across each 16-lane group: xor1, xor2 (quad_perm), half_mirror, mirror
    int v;
    v = __builtin_amdgcn_update_dpp(0, __float_as_int(x), 0xB1,  0xF, 0xF, true);
    x += __int_as_float(v);
    v = __builtin_amdgcn_update_dpp(0, __float_as_int(x), 0x4E,  0xF, 0xF, true);
    x += __int_as_float(v);
    v = __builtin_amdgcn_update_dpp(0, __float_as_int(x), 0x141, 0xF, 0xF, true);
    x += __int_as_float(v);
    v = __builtin_amdgcn_update_dpp(0, __float_as_int(x), 0x140, 0xF, 0xF, true);
    x += __int_as_float(v);
    return x;
}

__device__ __forceinline__ float row_term(f32x4 p, int t, int cbase,
                                          float K0, float K1, float Ke) {
    // full-row exp-sum (only cross-lane reduction needed)
    float es = __expf(p.x) + __expf(p.y) + __expf(p.z) + __expf(p.w);
    es = dpp_add16(es);
    const float lse = __logf(es);

    // else-branch weights: w = max(0, 0.34 - 0.10 d - 0.01 d^2), d=|j-2|,
    // j=(c - t + 37) & 63  (exact at d=0,1,2 to ~1e-8; <0 for d>=3)
    const int j0 = cbase - t + 37;
    float w[4], pp[4] = {p.x, p.y, p.z, p.w};
    #pragma unroll
    for (int k = 0; k < 4; ++k) {
        const int j = (j0 + k) & 63;
        const float d = fabsf((float)(j - 2));
        w[k] = fmaxf(0.0f, __fmaf_rn(d, __fmaf_rn(d, -0.01f, -0.10f), 0.34f));
    }
    float K = Ke;
    const bool edge = (t < 2) | (t >= 62);
    if (__any(edge)) {                    // ~40% of wave-iters
        const bool mir = (t >= 62);
        const int  tt  = mir ? 63 - t : t;        // 0 or 1 for edge lanes
        const float a0 = tt ? 0.25f : 0.60f;
        const float a1 = tt ? 0.40f : 0.25f;
        const float a2 = tt ? 0.25f : 0.15f;
        const float a3 = tt ? 0.10f : 0.00f;
        #pragma unroll
        for (int k = 0; k < 4; ++k) {
            const int cc = mir ? 63 - (cbase + k) : (cbase + k);
            const float we = (cc == 0) ? a0 : (cc == 1) ? a1
                           : (cc == 2) ? a2 : (cc == 3) ? a3 : 0.0f;
            if (edge) w[k] = we;
        }
        if (edge) K = tt ? K1 : K0;
    }
    float wp = 0.0f;
    #pragma unroll
    for (int k = 0; k < 4; ++k) wp = __fmaf_rn(w[k], pp[k], wp);
    // (K+lse) counted once per row: scale by 1/16; wp stays per-lane.
    return __fmaf_rn(K + lse, 0.0625f, -wp);
}

__global__ __launch_bounds__(THREADS, 8)
void fce_main(const float* __restrict__ pred, const int* __restrict__ target,
              unsigned int* __restrict__ counter,
              unsigned long long* __restrict__ gsum,
              float* __restrict__ out, int ngroups,
              float K0, float K1, float Ke, double outscale) {
    const int tid   = threadIdx.x;
    const int lane  = tid & 63;
    const int wid   = tid >> 6;
    const int s     = lane >> 4;        // subgroup 0..3
    const int cbase = (lane & 15) * 4;  // this lane's first column
    const int gw    = blockIdx.x * 4 + wid;
    const int nw    = gridDim.x * 4;

    float acc = 0.0f;

    for (int g = gw; g < ngroups; g += nw) {
        const float* base = pred + (size_t)g * (RPI * 64) + (2 * s) * 64 + cbase;
        const f32x4 a = __builtin_nontemporal_load(
            reinterpret_cast<const f32x4*>(base));
        const f32x4 b = __builtin_nontemporal_load(
            reinterpret_cast<const f32x4*>(base + 64));
        const i32x2 t2 = __builtin_nontemporal_load(
            reinterpret_cast<const i32x2*>(target + (size_t)g * RPI + 2 * s));
        acc += row_term(a, t2.x, cbase, K0, K1, Ke);
        acc += row_term(b, t2.y, cbase, K0, K1, Ke);
    }

    // wave sum (collects per-lane wp parts + 1/16-scaled row terms)
    #pragma unroll
    for (int m = 1; m < 64; m <<= 1) acc += __shfl_xor(acc, m);

    __shared__ float sred[4];
    __shared__ int lastflag;
    if (lane == 0) sred[wid] = acc;
    __syncthreads();
    if (tid == 0) {
        const float bsum = sred[0] + sred[1] + sred[2] + sred[3];
        // fixed-point accumulate: bit-deterministic across blocks/replays
        const long long q = (long long)llrintf(bsum * 274877906944.0f); // 2^38
        __hip_atomic_fetch_add(gsum, (unsigned long long)q,
                               __ATOMIC_RELEASE, __HIP_MEMORY_SCOPE_AGENT);
        const unsigned int prev = __hip_atomic_fetch_add(
            counter, 1u, __ATOMIC_ACQ_REL, __HIP_MEMORY_SCOPE_AGENT);
        lastflag = (prev == (unsigned)(gridDim.x - 1));
    }
    __syncthreads();
    if (lastflag && tid == 0) {
        const unsigned long long sv = __hip_atomic_load(
            gsum, __ATOMIC_ACQUIRE, __HIP_MEMORY_SCOPE_AGENT);
        out[0] = (float)((double)(long long)sv * outscale);
    }
}

extern "C" void kernel_launch(void* const* d_in, const int* in_sizes, int n_in,
                              void* d_out, int out_size, void* d_ws, size_t ws_size,
                              hipStream_t stream) {
    const float* pred = (const float*)d_in[0];
    const int* target = (const int*)d_in[1];
    unsigned int* counter = (unsigned int*)d_ws;
    unsigned long long* gsum = (unsigned long long*)((char*)d_ws + 8);
    float* out = (float*)d_out;

    const int B = in_sizes[1];       // 1048576 rows
    const int ngroups = B / RPI;     // 131072 groups of 8 rows

    const float K0 = 0.60f * logf(0.60f) + 0.25f * logf(0.25f) + 0.15f * logf(0.15f);
    const float K1 = 0.25f * logf(0.25f) + 0.40f * logf(0.40f)
                   + 0.25f * logf(0.25f) + 0.10f * logf(0.10f);
    const float Ke = 2.0f * 0.10f * logf(0.10f) + 2.0f * 0.23f * logf(0.23f)
                   + 0.34f * logf(0.34f);
    const double outscale = 1.0 / (274877906944.0 * (double)B);

    hipMemsetAsync(d_ws, 0, 16, stream);
    fce_main<<<NBLOCKS, THREADS, 0, stream>>>(pred, target, counter, gsum, out,
                                              ngroups, K0, K1, Ke, outscale);
}

// Round 5
// 177.876 us; speedup vs baseline: 1.2744x; 1.2744x over previous
//
#include <hip/hip_runtime.h>
#include <math.h>

// FilteredCrossEntropyLoss: B=1048576 rows, C=64 classes.
// loss = (1/B) * sum_rows [ K(t) + log(sum_c exp(p_c)) - sum_j f_j * p[col_j] ]
// All filters sum to 1; K(t)=sum f log f. No max-subtraction (inputs N(0,1)).
//
// Round-5 structure (round-3 load path + round-4 arithmetic wins):
//  - 16-lane group per row, 4 rows/wave-iter; ONE dwordx4/lane -> the wave
//    streams 1 KB fully contiguous. PLAIN loads (round 4 proved
//    nontemporal loads collapse to ~620 GB/s on gfx950 -- never again).
//  - weights computed in-lane (quadratic in d=|j-2|), edge rows fixed up
//    under a __any gate; wp stays per-lane (collected by final wave sum);
//    only exp-sum needs the 4-step DPP reduce. Zero DS ops in the loop.
//  - single kernel: block sums -> fixed-point (2^38) int64 atomicAdd
//    (bit-deterministic) + counter; last block writes d_out. 16 B memset.

#define THREADS 256
#define NBLOCKS 2048

typedef float f32x4 __attribute__((ext_vector_type(4)));

__device__ __forceinline__ float dpp_add16(float x) {
    // sum across each 16-lane group: xor1, xor2 (quad_perm), half_mirror, mirror
    int v;
    v = __builtin_amdgcn_update_dpp(0, __float_as_int(x), 0xB1,  0xF, 0xF, true);
    x += __int_as_float(v);
    v = __builtin_amdgcn_update_dpp(0, __float_as_int(x), 0x4E,  0xF, 0xF, true);
    x += __int_as_float(v);
    v = __builtin_amdgcn_update_dpp(0, __float_as_int(x), 0x141, 0xF, 0xF, true);
    x += __int_as_float(v);
    v = __builtin_amdgcn_update_dpp(0, __float_as_int(x), 0x140, 0xF, 0xF, true);
    x += __int_as_float(v);
    return x;
}

__device__ __forceinline__ float row_term(f32x4 p, int t, int cbase,
                                          float K0, float K1, float Ke) {
    // full-row exp-sum (the only cross-lane reduction)
    float es = __expf(p.x) + __expf(p.y) + __expf(p.z) + __expf(p.w);
    es = dpp_add16(es);
    const float lse = __logf(es);

    // else-branch weights: w = max(0, 0.34 - 0.10 d - 0.01 d^2), d=|j-2|,
    // j=(c - t + 37) & 63  (exact at d=0,1,2; <0 for d>=3)
    const int j0 = cbase - t + 37;
    float w[4], pp[4] = {p.x, p.y, p.z, p.w};
    #pragma unroll
    for (int k = 0; k < 4; ++k) {
        const int j = (j0 + k) & 63;
        const float d = fabsf((float)(j - 2));
        w[k] = fmaxf(0.0f, __fmaf_rn(d, __fmaf_rn(d, -0.01f, -0.10f), 0.34f));
    }
    float K = Ke;
    const bool edge = (t < 2) | (t >= 62);
    if (__any(edge)) {                    // ~23% of wave-iters
        const bool mir = (t >= 62);
        const int  tt  = mir ? 63 - t : t;        // 0 or 1 for edge lanes
        const float a0 = tt ? 0.25f : 0.60f;
        const float a1 = tt ? 0.40f : 0.25f;
        const float a2 = tt ? 0.25f : 0.15f;
        const float a3 = tt ? 0.10f : 0.00f;
        #pragma unroll
        for (int k = 0; k < 4; ++k) {
            const int cc = mir ? 63 - (cbase + k) : (cbase + k);
            const float we = (cc == 0) ? a0 : (cc == 1) ? a1
                           : (cc == 2) ? a2 : (cc == 3) ? a3 : 0.0f;
            if (edge) w[k] = we;
        }
        if (edge) K = tt ? K1 : K0;
    }
    float wp = 0.0f;
    #pragma unroll
    for (int k = 0; k < 4; ++k) wp = __fmaf_rn(w[k], pp[k], wp);
    // (K+lse) counted once per row via 1/16 scale; wp stays per-lane.
    return __fmaf_rn(K + lse, 0.0625f, -wp);
}

__global__ __launch_bounds__(THREADS, 8)
void fce_main(const float* __restrict__ pred, const int* __restrict__ target,
              unsigned int* __restrict__ counter,
              unsigned long long* __restrict__ gsum,
              float* __restrict__ out, int ngroups,
              float K0, float K1, float Ke, double outscale) {
    const int tid   = threadIdx.x;
    const int lane  = tid & 63;
    const int wid   = tid >> 6;
    const int sub   = lane >> 4;        // which of the wave's 4 rows
    const int cbase = (lane & 15) * 4;  // this lane's first column
    const int gw    = blockIdx.x * 4 + wid;
    const int nw    = NBLOCKS * 4;

    float acc = 0.0f;

    for (int g = gw; g < ngroups; g += nw) {
        // wave-contiguous 1 KB pred stream (4 rows), plain cached load
        const f32x4 p = *reinterpret_cast<const f32x4*>(
            pred + (size_t)g * 256 + (size_t)lane * 4);
        const int t = target[g * 4 + sub];
        acc += row_term(p, t, cbase, K0, K1, Ke);
    }

    // wave sum (collects per-lane wp parts + 1/16-scaled row terms)
    #pragma unroll
    for (int m = 1; m < 64; m <<= 1) acc += __shfl_xor(acc, m);

    __shared__ float sred[4];
    __shared__ int lastflag;
    if (lane == 0) sred[wid] = acc;
    __syncthreads();
    if (tid == 0) {
        const float bsum = sred[0] + sred[1] + sred[2] + sred[3];
        // fixed-point accumulate: bit-deterministic across blocks/replays
        const long long q = (long long)llrintf(bsum * 274877906944.0f); // 2^38
        __hip_atomic_fetch_add(gsum, (unsigned long long)q,
                               __ATOMIC_RELEASE, __HIP_MEMORY_SCOPE_AGENT);
        const unsigned int prev = __hip_atomic_fetch_add(
            counter, 1u, __ATOMIC_ACQ_REL, __HIP_MEMORY_SCOPE_AGENT);
        lastflag = (prev == (unsigned)(NBLOCKS - 1));
    }
    __syncthreads();
    if (lastflag && tid == 0) {
        const unsigned long long sv = __hip_atomic_load(
            gsum, __ATOMIC_ACQUIRE, __HIP_MEMORY_SCOPE_AGENT);
        out[0] = (float)((double)(long long)sv * outscale);
    }
}

extern "C" void kernel_launch(void* const* d_in, const int* in_sizes, int n_in,
                              void* d_out, int out_size, void* d_ws, size_t ws_size,
                              hipStream_t stream) {
    const float* pred = (const float*)d_in[0];
    const int* target = (const int*)d_in[1];
    unsigned int* counter = (unsigned int*)d_ws;
    unsigned long long* gsum = (unsigned long long*)((char*)d_ws + 8);
    float* out = (float*)d_out;

    const int B = in_sizes[1];       // 1048576 rows
    const int ngroups = B / 4;       // 262144 groups of 4 rows

    const float K0 = 0.60f * logf(0.60f) + 0.25f * logf(0.25f) + 0.15f * logf(0.15f);
    const float K1 = 0.25f * logf(0.25f) + 0.40f * logf(0.40f)
                   + 0.25f * logf(0.25f) + 0.10f * logf(0.10f);
    const float Ke = 2.0f * 0.10f * logf(0.10f) + 2.0f * 0.23f * logf(0.23f)
                   + 0.34f * logf(0.34f);
    const double outscale = 1.0 / (274877906944.0 * (double)B);

    hipMemsetAsync(d_ws, 0, 16, stream);
    fce_main<<<NBLOCKS, THREADS, 0, stream>>>(pred, target, counter, gsum, out,
                                              ngroups, K0, K1, Ke, outscale);
}

// Round 6
// 51.592 us; speedup vs baseline: 4.3939x; 3.4477x over previous
//
#include <hip/hip_runtime.h>
#include <math.h>

// FilteredCrossEntropyLoss: B=1048576 rows, C=64 classes.
// loss = (1/B) * sum_rows [ K(t) + log(sum_c exp(p_c)) - sum_j f_j * p[col_j] ]
// All filters sum to 1; K(t)=sum f log f. No max-subtraction (inputs N(0,1)).
//
// Round-6 = controlled A/B against round 3 (58.4 us known-good):
//   round-3 skeleton VERBATIM (two kernels, partial[] + fce_reduce, plain
//   float4 loads, no atomics/fences/memset -- rounds 4/5's fused atomic
//   epilogue is suspect #1 for their 4x slowdown at identical loop memory
//   shape), with ONE delta: the 5 L1 tap gathers are replaced by in-lane
//   quadratic weights (validated bit-exact in rounds 4/5). wp stays per-lane
//   (collected by the final wave butterfly); (K+lse) scaled by 1/16.

#define THREADS 256
#define NBLOCKS 2048

__device__ __forceinline__ float dpp_add16(float x) {
    // sum across each 16-lane group: xor1, xor2 (quad_perm), half_mirror, mirror
    int v;
    v = __builtin_amdgcn_update_dpp(0, __float_as_int(x), 0xB1,  0xF, 0xF, true);
    x += __int_as_float(v);
    v = __builtin_amdgcn_update_dpp(0, __float_as_int(x), 0x4E,  0xF, 0xF, true);
    x += __int_as_float(v);
    v = __builtin_amdgcn_update_dpp(0, __float_as_int(x), 0x141, 0xF, 0xF, true);
    x += __int_as_float(v);
    v = __builtin_amdgcn_update_dpp(0, __float_as_int(x), 0x140, 0xF, 0xF, true);
    x += __int_as_float(v);
    return x;
}

__global__ __launch_bounds__(THREADS, 8)
void fce_main(const float* __restrict__ pred, const int* __restrict__ target,
              float* __restrict__ partial, int ngroups,
              float K0, float K1, float Ke) {
    const int tid   = threadIdx.x;
    const int lane  = tid & 63;
    const int wid   = tid >> 6;
    const int sub   = lane >> 4;         // which of the wave's 4 rows
    const int cbase = (lane & 15) * 4;   // this lane's first column
    const int gw    = blockIdx.x * 4 + wid;
    const int nw    = gridDim.x * 4;

    float acc = 0.0f;

    for (int g = gw; g < ngroups; g += nw) {
        // wave-contiguous 1 KB pred stream (4 rows), plain cached load
        const float4 p4 = *reinterpret_cast<const float4*>(
            pred + (size_t)g * 256 + (size_t)lane * 4);
        const int t = target[g * 4 + sub];

        float pp[4] = {p4.x, p4.y, p4.z, p4.w};

        // ---- row exp-sum: 4 exps + DPP 16-lane reduce (no DS pipe) ----
        float es = __expf(pp[0]) + __expf(pp[1]) + __expf(pp[2]) + __expf(pp[3]);
        es = dpp_add16(es);
        const float lse = __logf(es);

        // ---- in-lane weights: w = max(0, 0.34 - 0.10 d - 0.01 d^2),
        //      d=|j-2|, j=(c - t + 37) & 63  (exact at d=0,1,2; <0 for d>=3)
        const int j0 = cbase - t + 37;
        float w[4];
        #pragma unroll
        for (int k = 0; k < 4; ++k) {
            const int j = (j0 + k) & 63;
            const float d = fabsf((float)(j - 2));
            w[k] = fmaxf(0.0f, __fmaf_rn(d, __fmaf_rn(d, -0.01f, -0.10f), 0.34f));
        }
        float K = Ke;
        const bool edge = (t < 2) | (t >= 62);
        if (__any(edge)) {                    // ~23% of wave-iters
            const bool mir = (t >= 62);
            const int  tt  = mir ? 63 - t : t;        // 0 or 1 for edge lanes
            const float a0 = tt ? 0.25f : 0.60f;
            const float a1 = tt ? 0.40f : 0.25f;
            const float a2 = tt ? 0.25f : 0.15f;
            const float a3 = tt ? 0.10f : 0.00f;
            #pragma unroll
            for (int k = 0; k < 4; ++k) {
                const int cc = mir ? 63 - (cbase + k) : (cbase + k);
                const float we = (cc == 0) ? a0 : (cc == 1) ? a1
                               : (cc == 2) ? a2 : (cc == 3) ? a3 : 0.0f;
                if (edge) w[k] = we;
            }
            if (edge) K = tt ? K1 : K0;
        }
        float wp = 0.0f;
        #pragma unroll
        for (int k = 0; k < 4; ++k) wp = __fmaf_rn(w[k], pp[k], wp);

        // (K+lse) counted once per row via 1/16 scale; wp stays per-lane
        acc += __fmaf_rn(K + lse, 0.0625f, -wp);
    }

    // full wave butterfly (acc is per-lane now)
    #pragma unroll
    for (int m = 1; m < 64; m <<= 1) acc += __shfl_xor(acc, m);

    __shared__ float sred[4];
    if (lane == 0) sred[wid] = acc;
    __syncthreads();
    if (tid == 0)
        partial[blockIdx.x] = sred[0] + sred[1] + sred[2] + sred[3];
}

__global__ __launch_bounds__(THREADS)
void fce_reduce(const float* __restrict__ partial, int n,
                float* __restrict__ out, float invB) {
    float s = 0.0f;
    for (int i = threadIdx.x; i < n; i += THREADS) s += partial[i];
    #pragma unroll
    for (int m = 1; m < 64; m <<= 1) s += __shfl_xor(s, m);
    __shared__ float ws[4];
    const int wid = threadIdx.x >> 6;
    if ((threadIdx.x & 63) == 0) ws[wid] = s;
    __syncthreads();
    if (threadIdx.x == 0)
        out[0] = (ws[0] + ws[1] + ws[2] + ws[3]) * invB;
}

extern "C" void kernel_launch(void* const* d_in, const int* in_sizes, int n_in,
                              void* d_out, int out_size, void* d_ws, size_t ws_size,
                              hipStream_t stream) {
    const float* pred  = (const float*)d_in[0];
    const int* target  = (const int*)d_in[1];
    float* partial     = (float*)d_ws;
    float* out         = (float*)d_out;

    const int B = in_sizes[1];      // 1048576 rows
    const int ngroups = B / 4;      // 262144 groups of 4 rows

    const float K0 = 0.60f * logf(0.60f) + 0.25f * logf(0.25f) + 0.15f * logf(0.15f);
    const float K1 = 0.25f * logf(0.25f) + 0.40f * logf(0.40f)
                   + 0.25f * logf(0.25f) + 0.10f * logf(0.10f);
    const float Ke = 2.0f * 0.10f * logf(0.10f) + 2.0f * 0.23f * logf(0.23f)
                   + 0.34f * logf(0.34f);

    fce_main<<<NBLOCKS, THREADS, 0, stream>>>(pred, target, partial, ngroups,
                                              K0, K1, Ke);
    fce_reduce<<<1, THREADS, 0, stream>>>(partial, NBLOCKS, out, 1.0f / (float)B);
}